// Round 10
// baseline (317.441 us; speedup 1.0000x reference)
//
#include <hip/hip_runtime.h>

// Problem constants
#define B_  8
#define C_  64
#define O_  64
#define H_  80
#define W_  800
#define NCHM   25          // main kernel: 800/32 exact 32-px chunks

#define ROWS_  10          // staged halo rows: h0-3 .. h0+6 (4 output rows)
#define ROWPX_ 44          // staged cols w0-4 .. w0+39 (quad-aligned)
#define ROWB_  5648u       // 44*128 + 16 pad: rows rotate bank-quads (write spread)
#define LDSX_BYTES (ROWS_ * 5648)      // 56480 B -> 2 blocks/CU @ 512 thr
#define NTASK  880         // 8 ch-groups * 10 rows * 11 px-quads

typedef short bf16x8 __attribute__((ext_vector_type(8)));
typedef float f32x4  __attribute__((ext_vector_type(4)));

__device__ __forceinline__ unsigned short f2bf(float f) {
    unsigned int u = __float_as_uint(f);
    unsigned int r = u + 0x7FFFu + ((u >> 16) & 1u);   // RNE
    return (unsigned short)(r >> 16);
}

// ---------------------------------------------------------------------------
// Kernel 1: pre-swizzle weight (9,O,C) fp32 into exact A-fragment order, bf16.
// ---------------------------------------------------------------------------
__global__ void k_wfrag(const float* __restrict__ wt, unsigned short* __restrict__ wf) {
    const int t = blockIdx.x * 256 + threadIdx.x;   // < 36864
    const int j    = t & 7;
    const int lane = (t >> 3) & 63;
    const int mt   = (t >> 9) & 3;
    const int ks   = t >> 11;                       // 0..17
    const int tap  = ks >> 1, hf = ks & 1;
    const int o = mt * 16 + (lane & 15);
    const int c = hf * 32 + (lane >> 4) * 8 + j;
    wf[t] = f2bf(wt[(tap * 64 + o) * 64 + c]);
}

// ---------------------------------------------------------------------------
// Kernel 2: FUSED transpose + gather-GEMM, single pass over x.
// Block = 512 thr = 8 waves over (4 h rows) x (2 o-halves); 32-px chunk.
//
// Stage v5 (fixes round-9's two measured misses):
//  * sched_barrier(0) between phase A (16 global float4 loads) and phase B
//    (pack+LDS write): hard fence -> compiler CANNOT fold B into A's loop;
//    all loads issue first, one latency round-trip. (R4/R8/R9 all showed
//    VGPR=52 = per-task serialization despite source-level split.)
//  * task = (g, row, q): q fastest keeps 11-lane 176-B coalesced runs
//    (R4's 65-MB FETCH), row diversity (~6 rows/wave) rotates write
//    bank-quads via the +16 row pad (bank-quad = (row+g+4q+i)&7).
//  * invalid T clamps to T-512 = this thread's it=0 task: redundant loads
//    are same-wave duplicate lines (L2 broadcast), not junk fetches
//    (R9's clamp-to-879 inflated FETCH 74->86.5 MB).
// Phase B and all gather/K-loop/epilogue addressing byte-identical to the
// PASSING round-9 kernel (incl. pad-safe colb^64 group rotation).
// ---------------------------------------------------------------------------
__global__ void __launch_bounds__(512, 4)
k_main(const float* __restrict__ x,
       const unsigned short* __restrict__ wfrag,
       const float* __restrict__ dh, const float* __restrict__ dw,
       const float* __restrict__ bias, float* __restrict__ out) {
    __shared__ __attribute__((aligned(16))) char lx[LDSX_BYTES];
    const int tid  = threadIdx.x;
    const int wave = tid >> 6, lane = tid & 63;

    const unsigned int flat = blockIdx.x;           // 0..3999
    const int b = flat & 7;                         // XCD swizzle: batch per XCD
    const unsigned int l = flat >> 3;               // 0..499
    const int chunk = l % NCHM;
    const int hq    = l / NCHM;                     // 0..19
    const int h0 = hq * 4;
    const int w0 = chunk * 32;
    const int h   = h0 + (wave & 3);
    const int mtb = (wave >> 2) * 2;                // o-half: mt in {mtb, mtb+1}
    const int l15 = lane & 15, kq = lane >> 4;

    // ---- Fused stage v5: fenced batched loads, then pack+write ----
    {
        f32x4 v[2][8];
        unsigned int wb[2];
        int swz[2], ok[2];
        // Phase A: ALL 16 loads issued; no consumer may be hoisted above the fence
#pragma unroll
        for (int it = 0; it < 2; ++it) {
            const int T  = tid + it * 512;              // 0..1023
            const int Tc = T < NTASK ? T : T - 512;     // invalid -> own it=0 task
            const int g   = Tc / 110;                   // ch-group 0..7
            const int rem = Tc - g * 110;
            const int row = rem / 11;                   // 0..9
            const int q   = rem - row * 11;             // px-quad 0..10 (fastest)
            const int ca  = w0 - 4 + 4 * q;             // absolute col of quad
            const int cac = ca < 0 ? 0 : (ca > W_ - 4 ? W_ - 4 : ca);
            int ar = h0 - 3 + row;
            ar = ar < 0 ? 0 : (ar > H_ - 1 ? H_ - 1 : ar);
            const float* s0 = x + ((size_t)(b * C_ + g * 8) * H_ + ar) * W_ + cac;
#pragma unroll
            for (int c = 0; c < 8; ++c)
                v[it][c] = *(const f32x4*)(s0 + (size_t)c * (H_ * W_));
            wb[it]  = (unsigned int)row * ROWB_ + (unsigned int)(4 * q) * 128u;
            swz[it] = g + ca;
            ok[it]  = (T < NTASK) & (ca >= 0) & (ca + 3 < W_);
        }
        __builtin_amdgcn_sched_barrier(0);   // loads above, consumers below
        // Phase B: pack + swizzled b128 writes (validity-gated)
#pragma unroll
        for (int it = 0; it < 2; ++it) {
            if (ok[it]) {
#pragma unroll
                for (int i = 0; i < 4; ++i) {
                    unsigned int u[4];
#pragma unroll
                    for (int j = 0; j < 4; ++j)
                        u[j] = (unsigned int)f2bf(v[it][2 * j][i])
                             | ((unsigned int)f2bf(v[it][2 * j + 1][i]) << 16);
                    char* dst = lx + wb[it] + (unsigned int)(i * 128)
                              + (unsigned int)(((swz[it] + i) & 7) << 4);
                    *(uint4*)dst = make_uint4(u[0], u[1], u[2], u[3]);
                }
            }
        }
    }

    // ---- Per-pixel gather addresses (LDS byte offsets) ----
    // 25*32 == 800 exactly: pw < W_ always, no clamps needed.
    unsigned int rowb[2][3], colb[2][3];
#pragma unroll
    for (int nt = 0; nt < 2; ++nt) {
        const int pw  = w0 + nt * 16 + l15;
        const int dhi = (int)dh[b * W_ + pw];
        const int dwi = (int)dw[b * W_ + pw];
        int rD = h - dhi;   if (rD < 0) rD = -rD;
        const int rU = (h + dhi < H_) ? (h + dhi) : h;
        int cL = pw - dwi;  if (cL < 0) cL = -cL;
        const int cR = (pw + dwi < W_) ? (pw + dwi) : (2 * W_ - 1 - pw - dwi);
        rowb[nt][0] = (unsigned int)(rD - h0 + 3) * ROWB_;
        rowb[nt][1] = (unsigned int)(h  - h0 + 3) * ROWB_;
        rowb[nt][2] = (unsigned int)(rU - h0 + 3) * ROWB_;
        const int cs[3] = {cL, pw, cR};
#pragma unroll
        for (int j = 0; j < 3; ++j)
            colb[nt][j] = (unsigned int)(cs[j] - (w0 - 4)) * 128u
                        + (unsigned int)(((cs[j] + kq) & 7) * 16);
    }

    const char* wfb = (const char*)wfrag;
    const unsigned int aoff = (unsigned int)lane * 16u;

    // acc init = bias
    f32x4 acc[2][2];
#pragma unroll
    for (int mtl = 0; mtl < 2; ++mtl) {
        const f32x4 bv = *(const f32x4*)(bias + (mtb + mtl) * 16 + kq * 4);
#pragma unroll
        for (int nt = 0; nt < 2; ++nt)
#pragma unroll
            for (int r = 0; r < 4; ++r) acc[mtl][nt][r] = bv[r];
    }

    __syncthreads();   // staging complete

    // ---- K loop: 18 steps; B dist-1 (LDS), A dist-2 (global) prefetch ----
    bf16x8 bcur[2], bnxt[2], a0[2], a1[2], a2[2];
#pragma unroll
    for (int nt = 0; nt < 2; ++nt)
        bcur[nt] = *(const bf16x8*)(lx + rowb[nt][0] + colb[nt][0]);
#pragma unroll
    for (int mtl = 0; mtl < 2; ++mtl) {
        a0[mtl] = *(const bf16x8*)(wfb + (unsigned int)((0 * 4 + mtb + mtl) * 1024) + aoff);
        a1[mtl] = *(const bf16x8*)(wfb + (unsigned int)((1 * 4 + mtb + mtl) * 1024) + aoff);
    }

#pragma unroll
    for (int s = 0; s < 18; ++s) {
        if (s < 17) {
            const int sn = s + 1;
            const int tap = sn >> 1, hf = sn & 1;
            const int i = tap / 3, j = tap % 3;
#pragma unroll
            for (int nt = 0; nt < 2; ++nt) {
                // group+=4 rotation on colb ONLY (pre-rowb): pad-safe
                const unsigned int cb = colb[nt][j] ^ (hf ? 64u : 0u);
                bnxt[nt] = *(const bf16x8*)(lx + rowb[nt][i] + cb);
            }
        }
        if (s < 16) {
#pragma unroll
            for (int mtl = 0; mtl < 2; ++mtl)
                a2[mtl] = *(const bf16x8*)(wfb
                            + (unsigned int)(((s + 2) * 4 + mtb + mtl) * 1024) + aoff);
        }
#pragma unroll
        for (int mtl = 0; mtl < 2; ++mtl)
#pragma unroll
            for (int nt = 0; nt < 2; ++nt)
                acc[mtl][nt] = __builtin_amdgcn_mfma_f32_16x16x32_bf16(
                    a0[mtl], bcur[nt], acc[mtl][nt], 0, 0, 0);
#pragma unroll
        for (int nt = 0; nt < 2; ++nt) bcur[nt] = bnxt[nt];
#pragma unroll
        for (int mtl = 0; mtl < 2; ++mtl) { a0[mtl] = a1[mtl]; a1[mtl] = a2[mtl]; }
    }

    // ---- Epilogue: out[b][o][h][w] (w always < W_: exact chunking) ----
#pragma unroll
    for (int mtl = 0; mtl < 2; ++mtl) {
#pragma unroll
        for (int nt = 0; nt < 2; ++nt) {
            const int w = w0 + nt * 16 + l15;
            const unsigned int ob =
                ((unsigned int)(b * O_ + (mtb + mtl) * 16 + kq * 4) * (unsigned int)H_
                 + (unsigned int)h) * (unsigned int)W_ + (unsigned int)w;
#pragma unroll
            for (int r = 0; r < 4; ++r)
                out[ob + (unsigned int)r * 64000u] = acc[mtl][nt][r];
        }
    }
}

extern "C" void kernel_launch(void* const* d_in, const int* in_sizes, int n_in,
                              void* d_out, int out_size, void* d_ws, size_t ws_size,
                              hipStream_t stream) {
    const float* x      = (const float*)d_in[0];   // (8,64,80,800)
    const float* dh     = (const float*)d_in[1];   // (8,1,800)
    const float* dw     = (const float*)d_in[2];   // (8,1,800)
    const float* weight = (const float*)d_in[3];   // (9,64,64)
    const float* bias   = (const float*)d_in[4];   // (64,)
    float* out = (float*)d_out;

    unsigned short* wfrag = (unsigned short*)d_ws; // 73,728 B only

    k_wfrag<<<dim3(144), 256, 0, stream>>>(weight, wfrag);
    k_main<<<dim3(NCHM * (H_ / 4) * B_), 512, 0, stream>>>(x, wfrag, dh, dw, bias, out);
}

// Round 11
// 299.031 us; speedup vs baseline: 1.0616x; 1.0616x over previous
//
#include <hip/hip_runtime.h>

// Problem constants
#define B_  8
#define C_  64
#define O_  64
#define H_  80
#define W_  800
#define NCHM   25          // main kernel: 800/32 exact 32-px chunks

#define ROWS_  10          // staged halo rows: h0-3 .. h0+6 (4 output rows)
#define ROWPX_ 44          // staged cols w0-4 .. w0+39 (quad-aligned)
#define ROWB_  5648u       // 44*128 + 16 pad: rows rotate bank-quads (write spread)
#define LDSX_BYTES (ROWS_ * 5648)      // 56480 B -> 2 blocks/CU @ 512 thr
#define NTASK  880         // 10 rows * 8 ch-groups * 11 px-quads

typedef short bf16x8 __attribute__((ext_vector_type(8)));
typedef float f32x4  __attribute__((ext_vector_type(4)));

__device__ __forceinline__ unsigned short f2bf(float f) {
    unsigned int u = __float_as_uint(f);
    unsigned int r = u + 0x7FFFu + ((u >> 16) & 1u);   // RNE
    return (unsigned short)(r >> 16);
}

// ---------------------------------------------------------------------------
// Kernel 1: pre-swizzle weight (9,O,C) fp32 into exact A-fragment order, bf16.
// ---------------------------------------------------------------------------
__global__ void k_wfrag(const float* __restrict__ wt, unsigned short* __restrict__ wf) {
    const int t = blockIdx.x * 256 + threadIdx.x;   // < 36864
    const int j    = t & 7;
    const int lane = (t >> 3) & 63;
    const int mt   = (t >> 9) & 3;
    const int ks   = t >> 11;                       // 0..17
    const int tap  = ks >> 1, hf = ks & 1;
    const int o = mt * 16 + (lane & 15);
    const int c = hf * 32 + (lane >> 4) * 8 + j;
    wf[t] = f2bf(wt[(tap * 64 + o) * 64 + c]);
}

// ---------------------------------------------------------------------------
// Kernel 2: FUSED transpose + gather-GEMM, single pass over x.
// Block = 512 thr = 8 waves over (4 h rows) x (2 o-halves); 32-px chunk.
//
// Stage v6: ASM-FORCED load batching. R4/R8/R9/R10 all compiled to VGPR=52 =
// per-task load serialization despite source splits / branch-free clamps /
// sched_barrier. Here the 16 global_load_dwordx4 are inline asm with "=&v"
// outputs: the data dependency runs through asm-defined registers, so the
// compiler CANNOT sink consumers into the load sequence; all 16 issue
// back-to-back (one HBM round-trip), then one manual s_waitcnt vmcnt(0) +
// sched_barrier(0) (rule #18) fences the packs.
//  * task = (row, g, q), q fastest: 11-lane 176-B coalesced runs (R9's
//    order, fastest of the family at 135 us).
//  * invalid T clamps to T-512 (own it=0 task): duplicate line = L2
//    broadcast, not junk fetch (R10 fix).
//  * launch_bounds(512,2): VGPR cap 256 so the 64 pinned data regs cannot
//    spill; LDS (56.5 KB) caps residency at 2 blocks/CU regardless.
// Phase B + gather/K-loop/epilogue byte-identical to the PASSING round-9/10
// kernels (incl. pad-safe colb^64 group rotation before adding rowb).
// ---------------------------------------------------------------------------
__global__ void __launch_bounds__(512, 2)
k_main(const float* __restrict__ x,
       const unsigned short* __restrict__ wfrag,
       const float* __restrict__ dh, const float* __restrict__ dw,
       const float* __restrict__ bias, float* __restrict__ out) {
    __shared__ __attribute__((aligned(16))) char lx[LDSX_BYTES];
    const int tid  = threadIdx.x;
    const int wave = tid >> 6, lane = tid & 63;

    const unsigned int flat = blockIdx.x;           // 0..3999
    const int b = flat & 7;                         // XCD swizzle: batch per XCD
    const unsigned int l = flat >> 3;               // 0..499
    const int chunk = l % NCHM;
    const int hq    = l / NCHM;                     // 0..19
    const int h0 = hq * 4;
    const int w0 = chunk * 32;
    const int h   = h0 + (wave & 3);
    const int mtb = (wave >> 2) * 2;                // o-half: mt in {mtb, mtb+1}
    const int l15 = lane & 15, kq = lane >> 4;

    // ---- Fused stage v6: asm-batched loads, fenced, then pack+write ----
    {
        f32x4 v[2][8];
        unsigned int wb[2];
        int swz[2], ok[2];
        // Phase A: issue ALL 16 loads via inline asm (results pinned in VGPRs)
#pragma unroll
        for (int it = 0; it < 2; ++it) {
            const int T  = tid + it * 512;              // 0..1023
            const int Tc = T < NTASK ? T : T - 512;     // invalid -> own it=0 task
            const int row = Tc / 88;                    // 0..9
            const int rem = Tc - row * 88;
            const int g   = rem / 11;                   // ch-group 0..7
            const int q   = rem - g * 11;               // px-quad 0..10 (fastest)
            const int ca  = w0 - 4 + 4 * q;             // absolute col of quad
            const int cac = ca < 0 ? 0 : (ca > W_ - 4 ? W_ - 4 : ca);
            int ar = h0 - 3 + row;
            ar = ar < 0 ? 0 : (ar > H_ - 1 ? H_ - 1 : ar);
            const float* s0 = x + ((size_t)(b * C_ + g * 8) * H_ + ar) * W_ + cac;
#pragma unroll
            for (int c = 0; c < 8; ++c) {
                const unsigned long long a =
                    (unsigned long long)(s0 + (size_t)c * (H_ * W_));
                asm volatile("global_load_dwordx4 %0, %1, off"
                             : "=&v"(v[it][c]) : "v"(a) : "memory");
            }
            wb[it]  = (unsigned int)row * ROWB_ + (unsigned int)(4 * q) * 128u;
            swz[it] = g + ca;
            ok[it]  = (T < NTASK) & (ca >= 0) & (ca + 3 < W_);
        }
        asm volatile("s_waitcnt vmcnt(0)" ::: "memory");
        __builtin_amdgcn_sched_barrier(0);   // nothing crosses: data valid below
        // Phase B: pack + swizzled b128 writes (validity-gated)
#pragma unroll
        for (int it = 0; it < 2; ++it) {
            if (ok[it]) {
#pragma unroll
                for (int i = 0; i < 4; ++i) {
                    unsigned int u[4];
#pragma unroll
                    for (int j = 0; j < 4; ++j)
                        u[j] = (unsigned int)f2bf(v[it][2 * j][i])
                             | ((unsigned int)f2bf(v[it][2 * j + 1][i]) << 16);
                    char* dst = lx + wb[it] + (unsigned int)(i * 128)
                              + (unsigned int)(((swz[it] + i) & 7) << 4);
                    *(uint4*)dst = make_uint4(u[0], u[1], u[2], u[3]);
                }
            }
        }
    }

    // ---- Per-pixel gather addresses (LDS byte offsets) ----
    // 25*32 == 800 exactly: pw < W_ always, no clamps needed.
    unsigned int rowb[2][3], colb[2][3];
#pragma unroll
    for (int nt = 0; nt < 2; ++nt) {
        const int pw  = w0 + nt * 16 + l15;
        const int dhi = (int)dh[b * W_ + pw];
        const int dwi = (int)dw[b * W_ + pw];
        int rD = h - dhi;   if (rD < 0) rD = -rD;
        const int rU = (h + dhi < H_) ? (h + dhi) : h;
        int cL = pw - dwi;  if (cL < 0) cL = -cL;
        const int cR = (pw + dwi < W_) ? (pw + dwi) : (2 * W_ - 1 - pw - dwi);
        rowb[nt][0] = (unsigned int)(rD - h0 + 3) * ROWB_;
        rowb[nt][1] = (unsigned int)(h  - h0 + 3) * ROWB_;
        rowb[nt][2] = (unsigned int)(rU - h0 + 3) * ROWB_;
        const int cs[3] = {cL, pw, cR};
#pragma unroll
        for (int j = 0; j < 3; ++j)
            colb[nt][j] = (unsigned int)(cs[j] - (w0 - 4)) * 128u
                        + (unsigned int)(((cs[j] + kq) & 7) * 16);
    }

    const char* wfb = (const char*)wfrag;
    const unsigned int aoff = (unsigned int)lane * 16u;

    // acc init = bias
    f32x4 acc[2][2];
#pragma unroll
    for (int mtl = 0; mtl < 2; ++mtl) {
        const f32x4 bv = *(const f32x4*)(bias + (mtb + mtl) * 16 + kq * 4);
#pragma unroll
        for (int nt = 0; nt < 2; ++nt)
#pragma unroll
            for (int r = 0; r < 4; ++r) acc[mtl][nt][r] = bv[r];
    }

    __syncthreads();   // staging complete

    // ---- K loop: 18 steps; B dist-1 (LDS), A dist-2 (global) prefetch ----
    bf16x8 bcur[2], bnxt[2], a0[2], a1[2], a2[2];
#pragma unroll
    for (int nt = 0; nt < 2; ++nt)
        bcur[nt] = *(const bf16x8*)(lx + rowb[nt][0] + colb[nt][0]);
#pragma unroll
    for (int mtl = 0; mtl < 2; ++mtl) {
        a0[mtl] = *(const bf16x8*)(wfb + (unsigned int)((0 * 4 + mtb + mtl) * 1024) + aoff);
        a1[mtl] = *(const bf16x8*)(wfb + (unsigned int)((1 * 4 + mtb + mtl) * 1024) + aoff);
    }

#pragma unroll
    for (int s = 0; s < 18; ++s) {
        if (s < 17) {
            const int sn = s + 1;
            const int tap = sn >> 1, hf = sn & 1;
            const int i = tap / 3, j = tap % 3;
#pragma unroll
            for (int nt = 0; nt < 2; ++nt) {
                // group+=4 rotation on colb ONLY (pre-rowb): pad-safe
                const unsigned int cb = colb[nt][j] ^ (hf ? 64u : 0u);
                bnxt[nt] = *(const bf16x8*)(lx + rowb[nt][i] + cb);
            }
        }
        if (s < 16) {
#pragma unroll
            for (int mtl = 0; mtl < 2; ++mtl)
                a2[mtl] = *(const bf16x8*)(wfb
                            + (unsigned int)(((s + 2) * 4 + mtb + mtl) * 1024) + aoff);
        }
#pragma unroll
        for (int mtl = 0; mtl < 2; ++mtl)
#pragma unroll
            for (int nt = 0; nt < 2; ++nt)
                acc[mtl][nt] = __builtin_amdgcn_mfma_f32_16x16x32_bf16(
                    a0[mtl], bcur[nt], acc[mtl][nt], 0, 0, 0);
#pragma unroll
        for (int nt = 0; nt < 2; ++nt) bcur[nt] = bnxt[nt];
#pragma unroll
        for (int mtl = 0; mtl < 2; ++mtl) { a0[mtl] = a1[mtl]; a1[mtl] = a2[mtl]; }
    }

    // ---- Epilogue: out[b][o][h][w] (w always < W_: exact chunking) ----
#pragma unroll
    for (int mtl = 0; mtl < 2; ++mtl) {
#pragma unroll
        for (int nt = 0; nt < 2; ++nt) {
            const int w = w0 + nt * 16 + l15;
            const unsigned int ob =
                ((unsigned int)(b * O_ + (mtb + mtl) * 16 + kq * 4) * (unsigned int)H_
                 + (unsigned int)h) * (unsigned int)W_ + (unsigned int)w;
#pragma unroll
            for (int r = 0; r < 4; ++r)
                out[ob + (unsigned int)r * 64000u] = acc[mtl][nt][r];
        }
    }
}

extern "C" void kernel_launch(void* const* d_in, const int* in_sizes, int n_in,
                              void* d_out, int out_size, void* d_ws, size_t ws_size,
                              hipStream_t stream) {
    const float* x      = (const float*)d_in[0];   // (8,64,80,800)
    const float* dh     = (const float*)d_in[1];   // (8,1,800)
    const float* dw     = (const float*)d_in[2];   // (8,1,800)
    const float* weight = (const float*)d_in[3];   // (9,64,64)
    const float* bias   = (const float*)d_in[4];   // (64,)
    float* out = (float*)d_out;

    unsigned short* wfrag = (unsigned short*)d_ws; // 73,728 B only

    k_wfrag<<<dim3(144), 256, 0, stream>>>(weight, wfrag);
    k_main<<<dim3(NCHM * (H_ / 4) * B_), 512, 0, stream>>>(x, wfrag, dh, dw, bias, out);
}